// Round 8
// baseline (92.900 us; speedup 1.0000x reference)
//
#include <hip/hip_runtime.h>

#define BATCH 8
#define NCLS  19
#define LOGN  18
#define NPIX  (1u << LOGN)      // 262144 pixels per image
#define NB    64                // histogram bins over p in [0,1)
#define BLK1  512
#define BPB   64                // blocks per image -> 4096 pixels per block
#define NPASS 3                 // PROBE: run main loop 3x so k_hist enters rocprof top-5
#define HCOPY 8                 // LDS histogram copies (lane & 7)
#define HSTR  (NCLS * NB + 4)   // 1220 words; copies start on distinct banks

// ---------------- Kernel 1 (R4-identical math, NPASS passes; counts become
// NPASS x true and are divided back in k_finish — exact for integers).
__global__ __launch_bounds__(BLK1, 4) void k_hist(
    const float* __restrict__ pred, const int* __restrict__ target,
    unsigned short* __restrict__ hist_part, float* __restrict__ s2_part)
{
    __shared__ unsigned hist[HCOPY * HSTR];       // 39040 B
    __shared__ float    s2w[BLK1 / 64][NCLS];

    const int b     = blockIdx.x / BPB;
    const int chunk = blockIdx.x % BPB;
    const int tid   = threadIdx.x;
    const int lane  = tid & 63;
    const int wid   = tid >> 6;

    unsigned* hpar = hist + (lane & (HCOPY - 1)) * HSTR;

    for (int i = tid; i < HCOPY * HSTR; i += BLK1) hist[i] = 0u;
    __syncthreads();

    float ps[NCLS];
    #pragma unroll
    for (int c = 0; c < NCLS; ++c) ps[c] = 0.0f;

    const float* pb   = pred + (((size_t)b * NCLS) << LOGN);
    const int*   tb   = target + ((size_t)b << LOGN);
    const int    base = chunk * (int)(NPIX / BPB);

    #pragma unroll 1
    for (int pass = 0; pass < NPASS; ++pass) {
        #pragma unroll 1
        for (int it = 0; it < (int)(NPIX / BPB) / (2 * BLK1); ++it) {   // 4 iters
            const int n = base + it * (2 * BLK1) + 2 * tid;

            const int2 tg = *reinterpret_cast<const int2*>(tb + n);

            float2 e2[NCLS];
            float sA = 0.0f, sB = 0.0f;
            #pragma unroll
            for (int c = 0; c < NCLS; ++c) {
                const float2 x = *reinterpret_cast<const float2*>(pb + (((size_t)c) << LOGN) + n);
                const float eA = __expf(x.x);
                const float eB = __expf(x.y);
                e2[c].x = eA; e2[c].y = eB;
                sA += eA; sB += eB;
            }
            const float rA = __builtin_amdgcn_rcpf(sA) * (float)NB;   // p*NB scale
            const float rB = __builtin_amdgcn_rcpf(sB) * (float)NB;

            #pragma unroll
            for (int c = 0; c < NCLS; ++c) {
                const float tA = e2[c].x * rA;
                const float tB = e2[c].y * rB;
                int binA = (int)tA; binA = binA > NB - 1 ? NB - 1 : binA;
                int binB = (int)tB; binB = binB > NB - 1 ? NB - 1 : binB;
                ps[c] += ((c == tg.x) ? fmaf(tA, -1.0f / (float)NB, 1.0f) : 0.0f)
                       + ((c == tg.y) ? fmaf(tB, -1.0f / (float)NB, 1.0f) : 0.0f);
                if (c != tg.x) atomicAdd(&hpar[c * NB + binA], 1u);
                if (c != tg.y) atomicAdd(&hpar[c * NB + binB], 1u);
            }
        }
    }
    __syncthreads();

    // s2: wave shuffle-reduce, then cross-wave via LDS (fixed order, deterministic)
    #pragma unroll
    for (int c = 0; c < NCLS; ++c) {
        float v = ps[c];
        #pragma unroll
        for (int off = 32; off > 0; off >>= 1) v += __shfl_down(v, off, 64);
        if (lane == 0) s2w[wid][c] = v;
    }
    __syncthreads();

    // write private u16 partials (3x true counts; max 3*4096 < 65535), transposed
    for (int i = tid; i < NCLS * NB; i += BLK1) {
        unsigned v = 0;
        #pragma unroll
        for (int k = 0; k < HCOPY; ++k) v += hist[k * HSTR + i];
        const int c = i >> 6, bin = i & (NB - 1);
        hist_part[((size_t)(b * NCLS + c) * BPB + chunk) * NB + bin] = (unsigned short)v;
    }
    if (tid < NCLS) {
        float v = 0.0f;
        #pragma unroll
        for (int w = 0; w < BLK1 / 64; ++w) v += s2w[w][tid];
        s2_part[(size_t)(b * NCLS + tid) * BPB + chunk] = v;
    }
}

// ---------------- Kernel 2: sum partials (/NPASS), wave suffix-scan, trapezoid
// loss_bc = M/N + sum_k (dx/2)*(g(S_k)+g(S_{k+1})) + S2/N,  g(r)=r/(n_c+r).
__global__ __launch_bounds__(256) void k_finish(
    const unsigned short* __restrict__ hist_part, const float* __restrict__ s2_part,
    float* __restrict__ loss_bc)
{
    __shared__ unsigned hsum[4][NB];

    const int bc   = blockIdx.x;
    const int tid  = threadIdx.x;
    const int lane = tid & 63;
    const int w    = tid >> 6;

    const unsigned short* hp = hist_part + (size_t)bc * BPB * NB;
    unsigned h = 0;
    #pragma unroll 1
    for (int k = 0; k < BPB / 4; ++k)
        h += hp[(size_t)(w * (BPB / 4) + k) * NB + lane];
    hsum[w][lane] = h;
    __syncthreads();

    if (w == 0) {
        const unsigned hb = (hsum[0][lane] + hsum[1][lane] + hsum[2][lane] + hsum[3][lane]) / NPASS;
        // lane l takes bin 63-l: lane prefix-scan == bin suffix-scan
        const unsigned hrev = __shfl(hb, 63 - lane, 64);
        unsigned sc = hrev;
        #pragma unroll
        for (int off = 1; off < 64; off <<= 1) {
            const unsigned v = __shfl_up(sc, off, 64);
            if (lane >= off) sc += v;
        }
        const unsigned M   = __shfl(sc, 63, 64);     // total non-target count
        const float    ncf = (float)(NPIX - M);      // n_c
        const unsigned Rh  = sc;                     // inclusive suffix count
        const unsigned Rab = sc - hrev;              // strictly-above count

        const float gR  = (Rab > 0) ? (float)Rab / ((float)Rab + ncf) : 0.0f;
        const float gRh = (Rh  > 0) ? (float)Rh  / ((float)Rh  + ncf) : 0.0f;

        float red = gR + gRh;
        float s2  = s2_part[(size_t)bc * BPB + lane] * (1.0f / (float)NPASS);
        #pragma unroll
        for (int off = 32; off > 0; off >>= 1) {
            red += __shfl_down(red, off, 64);
            s2  += __shfl_down(s2,  off, 64);
        }
        if (lane == 0) {
            const float Nf = (float)NPIX;
            loss_bc[bc] = (float)M / Nf + red * (0.5f / (float)NB) + s2 / Nf;
        }
    }
}

// ---------------- Kernel 3: deterministic tree-sum of the 152 per-(b,c) losses.
__global__ __launch_bounds__(256) void k_reduce(
    const float* __restrict__ loss_bc, float* __restrict__ out)
{
    __shared__ float r[256];
    const int tid = threadIdx.x;
    r[tid] = (tid < BATCH * NCLS) ? loss_bc[tid] : 0.0f;
    __syncthreads();
    for (int off = 128; off > 0; off >>= 1) {
        if (tid < off) r[tid] += r[tid + off];
        __syncthreads();
    }
    if (tid == 0) out[0] = r[0] * (1.0f / (float)(BATCH * NCLS));
}

extern "C" void kernel_launch(void* const* d_in, const int* in_sizes, int n_in,
                              void* d_out, int out_size, void* d_ws, size_t ws_size,
                              hipStream_t stream)
{
    const float* pred   = (const float*)d_in[0];
    const int*   target = (const int*)d_in[1];
    float*       out    = (float*)d_out;
    unsigned char* ws   = (unsigned char*)d_ws;

    unsigned short* hist_part = (unsigned short*)ws;   // 8*19*64*64 u16 = 1.25 MB
    float* s2_part = (float*)(ws + (size_t)BATCH * NCLS * BPB * NB * sizeof(unsigned short));
    float* loss_bc = (float*)((unsigned char*)s2_part + (size_t)BATCH * NCLS * BPB * sizeof(float));

    hipLaunchKernelGGL(k_hist,   dim3(BATCH * BPB),  dim3(BLK1), 0, stream,
                       pred, target, hist_part, s2_part);
    hipLaunchKernelGGL(k_finish, dim3(BATCH * NCLS), dim3(256),  0, stream,
                       hist_part, s2_part, loss_bc);
    hipLaunchKernelGGL(k_reduce, dim3(1),            dim3(256),  0, stream,
                       loss_bc, out);
}

// Round 9
// 56.635 us; speedup vs baseline: 1.6403x; 1.6403x over previous
//
#include <hip/hip_runtime.h>

#define BATCH 8
#define NCLS  19
#define LOGN  18
#define NPIX  (1u << LOGN)       // 262144 pixels per image
#define NB    64                 // histogram bins over p in [0,1)
#define BLK1  512
#define HCOPY 8                  // LDS histogram copies (lane & 7)
#define HSTR  (NCLS * NB + 4)    // 1220 words; copies start on distinct banks
#define TRASHW (HCOPY * HSTR)    // shared trash row for target-class atomics

// ---------------- Kernel 1: softmax + per-(b,c) histogram of non-target p.
// Latency-attack shape: 4 blocks/CU (launch_bounds(512,8), 39.9KB LDS) x
// 2 independent pixel chains/thread; tree-summed denominator (depth 5, not 19);
// branch-free class loop (target-class atomic redirected to trash row via
// cndmask -- no exec-mask branches); s2 via one ds_add_f32/px into per-wave rows.
template<int BPB>
__global__ __launch_bounds__(BLK1, 8) void k_hist(
    const float* __restrict__ pred, const int* __restrict__ target,
    unsigned short* __restrict__ hist_part, float* __restrict__ s2_part)
{
    constexpr int PPB = (int)(NPIX / BPB);

    __shared__ unsigned hist[HCOPY * HSTR + NB];   // 39296 B (incl. trash row)
    __shared__ float    s2l[BLK1 / 64][NCLS];      // per-wave s2 rows

    const int b     = blockIdx.x / BPB;
    const int chunk = blockIdx.x % BPB;
    const int tid   = threadIdx.x;
    const int lane  = tid & 63;
    const int wid   = tid >> 6;
    const unsigned hbase = (unsigned)(lane & (HCOPY - 1)) * HSTR;

    for (int i = tid; i < HCOPY * HSTR + NB; i += BLK1) hist[i] = 0u;
    if (tid < (BLK1 / 64) * NCLS) (&s2l[0][0])[tid] = 0.f;
    __syncthreads();

    const float* pb   = pred + (((size_t)b * NCLS) << LOGN);
    const int*   tb   = target + ((size_t)b << LOGN);
    const int    base = chunk * PPB;

    #pragma unroll 1
    for (int it = 0; it < PPB / (2 * BLK1); ++it) {
        const int n = base + it * (2 * BLK1) + 2 * tid;
        const int2 tg = *reinterpret_cast<const int2*>(tb + n);

        float2 e2[NCLS];
        #pragma unroll
        for (int c = 0; c < NCLS; ++c) {
            const float2 x = *reinterpret_cast<const float2*>(pb + (((size_t)c) << LOGN) + n);
            e2[c].x = __expf(x.x);
            e2[c].y = __expf(x.y);
        }
        // tree-summed denominators (depth ~5 instead of serial 19)
        const float sA =
            (((e2[0].x + e2[1].x) + (e2[2].x + e2[3].x)) + ((e2[4].x + e2[5].x) + (e2[6].x + e2[7].x)))
          + (((e2[8].x + e2[9].x) + (e2[10].x + e2[11].x)) + ((e2[12].x + e2[13].x) + (e2[14].x + e2[15].x)))
          + ((e2[16].x + e2[17].x) + e2[18].x);
        const float sB =
            (((e2[0].y + e2[1].y) + (e2[2].y + e2[3].y)) + ((e2[4].y + e2[5].y) + (e2[6].y + e2[7].y)))
          + (((e2[8].y + e2[9].y) + (e2[10].y + e2[11].y)) + ((e2[12].y + e2[13].y) + (e2[14].y + e2[15].y)))
          + ((e2[16].y + e2[17].y) + e2[18].y);

        const float rA = __builtin_amdgcn_rcpf(sA) * (float)NB;   // p*NB scale
        const float rB = __builtin_amdgcn_rcpf(sB) * (float)NB;

        float etA = 0.f, etB = 0.f;
        #pragma unroll
        for (int c = 0; c < NCLS; ++c) {
            const float tA = e2[c].x * rA;
            const float tB = e2[c].y * rB;
            int binA = (int)tA; binA = binA > NB - 1 ? NB - 1 : binA;
            int binB = (int)tB; binB = binB > NB - 1 ? NB - 1 : binB;
            const bool iA = (c == tg.x), iB = (c == tg.y);
            etA = iA ? e2[c].x : etA;                 // e^x of target class
            etB = iB ? e2[c].y : etB;
            const unsigned wA = iA ? (unsigned)TRASHW : hbase + c * NB;  // cndmask, no branch
            const unsigned wB = iB ? (unsigned)TRASHW : hbase + c * NB;
            atomicAdd(&hist[wA + (unsigned)binA], 1u);
            atomicAdd(&hist[wB + (unsigned)binB], 1u);
        }
        // s2 += (1 - p_tg), one LDS float atomic per pixel into this wave's row
        atomicAdd(&s2l[wid][tg.x], fmaf(etA * rA, -1.0f / (float)NB, 1.0f));
        atomicAdd(&s2l[wid][tg.y], fmaf(etB * rB, -1.0f / (float)NB, 1.0f));
    }
    __syncthreads();

    // transposed u16 partials: part[((b*NCLS+c)*BPB + chunk)*NB + bin]
    for (int i = tid; i < NCLS * NB; i += BLK1) {
        unsigned v = 0;
        #pragma unroll
        for (int k = 0; k < HCOPY; ++k) v += hist[k * HSTR + i];
        const int c = i >> 6, bin = i & (NB - 1);
        hist_part[((size_t)(b * NCLS + c) * BPB + chunk) * NB + bin] = (unsigned short)v;
    }
    if (tid < NCLS) {
        float v = 0.f;
        #pragma unroll
        for (int w = 0; w < BLK1 / 64; ++w) v += s2l[w][tid];
        s2_part[(size_t)(b * NCLS + tid) * BPB + chunk] = v;
    }
}

// ---------------- Kernel 2: per (b,c): sum partials, wave suffix-scan, trapezoid
// loss_bc = M/N + sum_k (dx/2)*(g(S_k)+g(S_{k+1})) + S2/N,  g(r)=r/(n_c+r),
// M = histogram total (bin 0 included), n_c = NPIX - M.
template<int BPB>
__global__ __launch_bounds__(256) void k_finish(
    const unsigned short* __restrict__ hist_part, const float* __restrict__ s2_part,
    float* __restrict__ loss_bc)
{
    __shared__ unsigned hsum[4][NB];
    __shared__ float s2tot;

    const int bc   = blockIdx.x;
    const int tid  = threadIdx.x;
    const int lane = tid & 63;
    const int w    = tid >> 6;

    const unsigned short* hp = hist_part + (size_t)bc * BPB * NB;
    unsigned h = 0;
    #pragma unroll 1
    for (int k = 0; k < BPB / 4; ++k)
        h += hp[(size_t)(w * (BPB / 4) + k) * NB + lane];
    hsum[w][lane] = h;

    if (w == 1) {
        float v = 0.f;
        for (int k = lane; k < BPB; k += 64) v += s2_part[(size_t)bc * BPB + k];
        #pragma unroll
        for (int off = 32; off > 0; off >>= 1) v += __shfl_down(v, off, 64);
        if (lane == 0) s2tot = v;
    }
    __syncthreads();

    if (w == 0) {
        const unsigned hb = hsum[0][lane] + hsum[1][lane] + hsum[2][lane] + hsum[3][lane];
        // lane l takes bin 63-l: lane prefix-scan == bin suffix-scan
        const unsigned hrev = __shfl(hb, 63 - lane, 64);
        unsigned sc = hrev;
        #pragma unroll
        for (int off = 1; off < 64; off <<= 1) {
            const unsigned v = __shfl_up(sc, off, 64);
            if (lane >= off) sc += v;
        }
        const unsigned M   = __shfl(sc, 63, 64);     // total non-target count
        const float    ncf = (float)(NPIX - M);      // n_c
        const unsigned Rh  = sc;                     // inclusive suffix count
        const unsigned Rab = sc - hrev;              // strictly-above count

        const float gR  = (Rab > 0) ? (float)Rab / ((float)Rab + ncf) : 0.0f;
        const float gRh = (Rh  > 0) ? (float)Rh  / ((float)Rh  + ncf) : 0.0f;

        float red = gR + gRh;
        #pragma unroll
        for (int off = 32; off > 0; off >>= 1) red += __shfl_down(red, off, 64);
        if (lane == 0) {
            const float Nf = (float)NPIX;
            loss_bc[bc] = (float)M / Nf + red * (0.5f / (float)NB) + s2tot / Nf;
        }
    }
}

// ---------------- Kernel 3: deterministic tree-sum of the 152 per-(b,c) losses.
__global__ __launch_bounds__(256) void k_reduce(
    const float* __restrict__ loss_bc, float* __restrict__ out)
{
    __shared__ float r[256];
    const int tid = threadIdx.x;
    r[tid] = (tid < BATCH * NCLS) ? loss_bc[tid] : 0.0f;
    __syncthreads();
    for (int off = 128; off > 0; off >>= 1) {
        if (tid < off) r[tid] += r[tid + off];
        __syncthreads();
    }
    if (tid == 0) out[0] = r[0] * (1.0f / (float)(BATCH * NCLS));
}

template<int BPB>
static void launch_all(const float* pred, const int* target, unsigned char* ws,
                       float* out, hipStream_t stream)
{
    unsigned short* hist_part = (unsigned short*)ws;
    float* s2_part = (float*)(ws + (size_t)BATCH * NCLS * BPB * NB * sizeof(unsigned short));
    float* loss_bc = (float*)((unsigned char*)s2_part + (size_t)BATCH * NCLS * BPB * sizeof(float));

    hipLaunchKernelGGL(k_hist<BPB>,   dim3(BATCH * BPB),  dim3(BLK1), 0, stream,
                       pred, target, hist_part, s2_part);
    hipLaunchKernelGGL(k_finish<BPB>, dim3(BATCH * NCLS), dim3(256),  0, stream,
                       hist_part, s2_part, loss_bc);
    hipLaunchKernelGGL(k_reduce,      dim3(1),            dim3(256),  0, stream,
                       loss_bc, out);
}

extern "C" void kernel_launch(void* const* d_in, const int* in_sizes, int n_in,
                              void* d_out, int out_size, void* d_ws, size_t ws_size,
                              hipStream_t stream)
{
    const float* pred   = (const float*)d_in[0];
    const int*   target = (const int*)d_in[1];
    float*       out    = (float*)d_out;
    unsigned char* ws   = (unsigned char*)d_ws;

    auto need = [](int bpb) {
        return (size_t)BATCH * NCLS * bpb * (NB * sizeof(unsigned short) + sizeof(float))
             + (size_t)BATCH * NCLS * sizeof(float);
    };

    if (ws_size >= need(128)) launch_all<128>(pred, target, ws, out, stream);
    else                      launch_all<64>(pred, target, ws, out, stream);
}

// Round 10
// 48.659 us; speedup vs baseline: 1.9092x; 1.1639x over previous
//
#include <hip/hip_runtime.h>

#define BATCH 8
#define NCLS  19
#define LOGN  18
#define NPIX  (1u << LOGN)      // 262144 pixels per image
#define NB    64                // histogram bins over p in [0,1)
#define BLK1  512
#define HCOPY 8                 // LDS histogram copies (lane & 7)
#define HSTR  (NCLS * NB + 4)   // 1220 words; copies start on distinct banks

// ---------------- Kernel 1: EXACT R4 champion body; only the grid changed
// (BPB 64 -> 128 => 4 blocks/CU, 32 waves/CU, float2 2-px chains kept).
template<int BPB>
__global__ __launch_bounds__(BLK1, 4) void k_hist(
    const float* __restrict__ pred, const int* __restrict__ target,
    unsigned short* __restrict__ hist_part, float* __restrict__ s2_part)
{
    __shared__ unsigned hist[HCOPY * HSTR];       // 39040 B
    __shared__ float    s2w[BLK1 / 64][NCLS];

    const int b     = blockIdx.x / BPB;
    const int chunk = blockIdx.x % BPB;
    const int tid   = threadIdx.x;
    const int lane  = tid & 63;
    const int wid   = tid >> 6;

    unsigned* hpar = hist + (lane & (HCOPY - 1)) * HSTR;

    for (int i = tid; i < HCOPY * HSTR; i += BLK1) hist[i] = 0u;
    __syncthreads();

    float ps[NCLS];
    #pragma unroll
    for (int c = 0; c < NCLS; ++c) ps[c] = 0.0f;

    const float* pb   = pred + (((size_t)b * NCLS) << LOGN);
    const int*   tb   = target + ((size_t)b << LOGN);
    const int    base = chunk * (int)(NPIX / BPB);

    #pragma unroll 1
    for (int it = 0; it < (int)(NPIX / BPB) / (2 * BLK1); ++it) {
        const int n = base + it * (2 * BLK1) + 2 * tid;

        const int2 tg = *reinterpret_cast<const int2*>(tb + n);

        float2 e2[NCLS];
        float sA = 0.0f, sB = 0.0f;
        #pragma unroll
        for (int c = 0; c < NCLS; ++c) {
            const float2 x = *reinterpret_cast<const float2*>(pb + (((size_t)c) << LOGN) + n);
            const float eA = __expf(x.x);
            const float eB = __expf(x.y);
            e2[c].x = eA; e2[c].y = eB;
            sA += eA; sB += eB;
        }
        const float rA = __builtin_amdgcn_rcpf(sA) * (float)NB;   // p*NB scale
        const float rB = __builtin_amdgcn_rcpf(sB) * (float)NB;

        #pragma unroll
        for (int c = 0; c < NCLS; ++c) {
            const float tA = e2[c].x * rA;
            const float tB = e2[c].y * rB;
            int binA = (int)tA; binA = binA > NB - 1 ? NB - 1 : binA;
            int binB = (int)tB; binB = binB > NB - 1 ? NB - 1 : binB;
            ps[c] += ((c == tg.x) ? fmaf(tA, -1.0f / (float)NB, 1.0f) : 0.0f)
                   + ((c == tg.y) ? fmaf(tB, -1.0f / (float)NB, 1.0f) : 0.0f);
            if (c != tg.x) atomicAdd(&hpar[c * NB + binA], 1u);
            if (c != tg.y) atomicAdd(&hpar[c * NB + binB], 1u);
        }
    }
    __syncthreads();

    // s2: wave shuffle-reduce, then cross-wave via LDS (fixed order, deterministic)
    #pragma unroll
    for (int c = 0; c < NCLS; ++c) {
        float v = ps[c];
        #pragma unroll
        for (int off = 32; off > 0; off >>= 1) v += __shfl_down(v, off, 64);
        if (lane == 0) s2w[wid][c] = v;
    }
    __syncthreads();

    // write private u16 partials, transposed: part[((b*NCLS+c)*BPB + chunk)*NB + bin]
    for (int i = tid; i < NCLS * NB; i += BLK1) {
        unsigned v = 0;
        #pragma unroll
        for (int k = 0; k < HCOPY; ++k) v += hist[k * HSTR + i];
        const int c = i >> 6, bin = i & (NB - 1);
        hist_part[((size_t)(b * NCLS + c) * BPB + chunk) * NB + bin] = (unsigned short)v;
    }
    if (tid < NCLS) {
        float v = 0.0f;
        #pragma unroll
        for (int w = 0; w < BLK1 / 64; ++w) v += s2w[w][tid];
        s2_part[(size_t)(b * NCLS + tid) * BPB + chunk] = v;
    }
}

// ---------------- Kernel 2: per (b,c): sum the BPB coalesced partials, wave
// suffix-scan, loss_bc = M/N + sum_k (dx/2)*(g(S_k)+g(S_{k+1})) + S2/N,
// g(r) = r/(n_c + r), n_c = NPIX - M, M = histogram total (bin 0 included).
template<int BPB>
__global__ __launch_bounds__(256) void k_finish(
    const unsigned short* __restrict__ hist_part, const float* __restrict__ s2_part,
    float* __restrict__ loss_bc)
{
    __shared__ unsigned hsum[4][NB];
    __shared__ float s2tot;

    const int bc   = blockIdx.x;
    const int tid  = threadIdx.x;
    const int lane = tid & 63;
    const int w    = tid >> 6;

    const unsigned short* hp = hist_part + (size_t)bc * BPB * NB;
    unsigned h = 0;
    #pragma unroll 1
    for (int k = 0; k < BPB / 4; ++k)
        h += hp[(size_t)(w * (BPB / 4) + k) * NB + lane];
    hsum[w][lane] = h;

    if (w == 1) {
        float v = 0.f;
        for (int k = lane; k < BPB; k += 64) v += s2_part[(size_t)bc * BPB + k];
        #pragma unroll
        for (int off = 32; off > 0; off >>= 1) v += __shfl_down(v, off, 64);
        if (lane == 0) s2tot = v;
    }
    __syncthreads();

    if (w == 0) {
        const unsigned hb = hsum[0][lane] + hsum[1][lane] + hsum[2][lane] + hsum[3][lane];
        // lane l takes bin 63-l: lane prefix-scan == bin suffix-scan
        const unsigned hrev = __shfl(hb, 63 - lane, 64);
        unsigned sc = hrev;
        #pragma unroll
        for (int off = 1; off < 64; off <<= 1) {
            const unsigned v = __shfl_up(sc, off, 64);
            if (lane >= off) sc += v;
        }
        const unsigned M   = __shfl(sc, 63, 64);     // total non-target count
        const float    ncf = (float)(NPIX - M);      // n_c
        const unsigned Rh  = sc;                     // inclusive suffix count
        const unsigned Rab = sc - hrev;              // strictly-above count

        const float gR  = (Rab > 0) ? (float)Rab / ((float)Rab + ncf) : 0.0f;
        const float gRh = (Rh  > 0) ? (float)Rh  / ((float)Rh  + ncf) : 0.0f;

        float red = gR + gRh;
        #pragma unroll
        for (int off = 32; off > 0; off >>= 1) red += __shfl_down(red, off, 64);
        if (lane == 0) {
            const float Nf = (float)NPIX;
            loss_bc[bc] = (float)M / Nf + red * (0.5f / (float)NB) + s2tot / Nf;
        }
    }
}

// ---------------- Kernel 3: deterministic tree-sum of the 152 per-(b,c) losses.
__global__ __launch_bounds__(256) void k_reduce(
    const float* __restrict__ loss_bc, float* __restrict__ out)
{
    __shared__ float r[256];
    const int tid = threadIdx.x;
    r[tid] = (tid < BATCH * NCLS) ? loss_bc[tid] : 0.0f;
    __syncthreads();
    for (int off = 128; off > 0; off >>= 1) {
        if (tid < off) r[tid] += r[tid + off];
        __syncthreads();
    }
    if (tid == 0) out[0] = r[0] * (1.0f / (float)(BATCH * NCLS));
}

template<int BPB>
static void launch_all(const float* pred, const int* target, unsigned char* ws,
                       float* out, hipStream_t stream)
{
    unsigned short* hist_part = (unsigned short*)ws;
    float* s2_part = (float*)(ws + (size_t)BATCH * NCLS * BPB * NB * sizeof(unsigned short));
    float* loss_bc = (float*)((unsigned char*)s2_part + (size_t)BATCH * NCLS * BPB * sizeof(float));

    hipLaunchKernelGGL(k_hist<BPB>,   dim3(BATCH * BPB),  dim3(BLK1), 0, stream,
                       pred, target, hist_part, s2_part);
    hipLaunchKernelGGL(k_finish<BPB>, dim3(BATCH * NCLS), dim3(256),  0, stream,
                       hist_part, s2_part, loss_bc);
    hipLaunchKernelGGL(k_reduce,      dim3(1),            dim3(256),  0, stream,
                       loss_bc, out);
}

extern "C" void kernel_launch(void* const* d_in, const int* in_sizes, int n_in,
                              void* d_out, int out_size, void* d_ws, size_t ws_size,
                              hipStream_t stream)
{
    const float* pred   = (const float*)d_in[0];
    const int*   target = (const int*)d_in[1];
    float*       out    = (float*)d_out;
    unsigned char* ws   = (unsigned char*)d_ws;

    auto need = [](int bpb) {
        return (size_t)BATCH * NCLS * bpb * (NB * sizeof(unsigned short) + sizeof(float))
             + (size_t)BATCH * NCLS * sizeof(float);
    };

    // 4 blocks/CU needs grid 1024 = BPB 128 (LDS 39.04KB x 4 = 156.2 <= 160)
    if (ws_size >= need(128)) launch_all<128>(pred, target, ws, out, stream);
    else                      launch_all<64>(pred, target, ws, out, stream);
}